// Round 9
// baseline (382.992 us; speedup 1.0000x reference)
//
#include <hip/hip_runtime.h>
#include <stdint.h>

#define B_ 256
#define N_ 256
#define F_ 64
#define H_ 512

typedef _Float16 f16;
typedef _Float16 f16x8 __attribute__((ext_vector_type(8)));
typedef _Float16 f16x4 __attribute__((ext_vector_type(4)));
typedef _Float16 f16x2 __attribute__((ext_vector_type(2)));
typedef float    f32x4 __attribute__((ext_vector_type(4)));

__device__ __forceinline__ float sigmoidf_(float x) {
    return 1.0f / (1.0f + __expf(-x));
}

// Counted-vmcnt barrier pair (T3/T4 pattern, round-5/8 proven):
#define BAR_ACQ(N) do { \
    asm volatile("s_waitcnt vmcnt(" #N ")" ::: "memory"); \
    __builtin_amdgcn_s_barrier(); \
    __builtin_amdgcn_sched_barrier(0); } while (0)
#define BAR_REL() do { \
    __builtin_amdgcn_sched_barrier(0); \
    __builtin_amdgcn_s_barrier(); } while (0)

// ---------------------------------------------------------------------------
// k_fsum v3: sigmoid + symmetrize + normalize + LAYER-1 GEMM, one block/batch.
// Phases:
//  1. stage: S = sigmoid(z_b) -> T (bijective 16B-chunk swizzle), col partials
//  2. rowsum (parallel LDS pass), Dv = rsqrt degrees
//  3. emit-pairs: thread owns unordered tile-pair {(I,J),(J,I)} (J<=I); reads
//     both 8x8 tiles to regs, computes nA for both (mirror = reg transpose,
//     nA symmetric), writes global nA AND writes nA back into T IN-PLACE
//     (pair ownership -> no cross-thread hazard).
//  4. GEMM: H1 = relu(nA_lds @ XW1t^T): A-frags from T (swizzled), B-frags
//     direct-from-global (XW1t 256KB, L2-hot), barrier-free, 8 waves.
// Replaces the separate k_gemm dispatch (saved ~40us + nA re-read + launch).
__global__ __launch_bounds__(512) void k_fsum(const float* __restrict__ z,
                                              const f16* __restrict__ XW1t,
                                              f16* __restrict__ nA,
                                              f16* __restrict__ H1) {
    __shared__ f16 T[256 * 256];         // 128 KB
    __shared__ float cpart[8][256];      // 8 KB
    __shared__ float rpart[256][2];      // 2 KB
    __shared__ float Dv[256];            // 1 KB   (~139 KB total, 1 block/CU)

    const int b = blockIdx.x;
    const int tid = threadIdx.x, lane = tid & 63, w = tid >> 6;
    const float* zb = z + (size_t)b * (N_ * N_);

    auto swz = [](int i) { return (i & 31) ^ (i >> 5); };

    // ---- 1. stage ----
    float colacc[4] = {0.f, 0.f, 0.f, 0.f};
    const int ch = lane >> 1, half = lane & 1;
    for (int r = 0; r < 32; r++) {
        int i = w * 32 + r;
        float4 v = *(const float4*)(zb + (size_t)i * N_ + lane * 4);
        float s0 = sigmoidf_(v.x), s1 = sigmoidf_(v.y),
              s2 = sigmoidf_(v.z), s3 = sigmoidf_(v.w);
        f16x4 sv = { (f16)s0, (f16)s1, (f16)s2, (f16)s3 };
        *(f16x4*)&T[i * 256 + ((ch ^ swz(i)) << 3) + half * 4] = sv;
        colacc[0] += s0; colacc[1] += s1; colacc[2] += s2; colacc[3] += s3;
    }
    #pragma unroll
    for (int k = 0; k < 4; k++) cpart[w][lane * 4 + k] = colacc[k];
    __syncthreads();

    // ---- 2. rowsum + Dv ----
    {
        int i = tid >> 1, h = tid & 1;
        float s = 0.f;
        #pragma unroll
        for (int c = 0; c < 16; c++) {
            int cc = h * 16 + c;
            f16x8 v = *(const f16x8*)&T[i * 256 + ((cc ^ swz(i)) << 3)];
            #pragma unroll
            for (int k = 0; k < 8; k++) s += (float)v[k];
        }
        rpart[i][h] = s;
    }
    __syncthreads();
    if (tid < 256) {
        float cs = 0.f;
        #pragma unroll
        for (int ww = 0; ww < 8; ww++) cs += cpart[ww][tid];
        float rs = rpart[tid][0] + rpart[tid][1];
        Dv[tid] = rsqrtf(1.0f + 1e-6f + 0.5f * (rs + cs));
    }
    __syncthreads();

    // ---- 3. emit-pairs (528 unordered pairs over 32x32 tile grid) ----
    f16* Ob = nA + (size_t)b * (N_ * N_);
    for (int pp = 0; pp < 2; pp++) {
        if (pp == 1 && tid >= 16) break;
        int p = pp * 512 + tid;                  // 0..527
        int I = (int)((sqrtf(8.0f * (float)p + 1.0f) - 1.0f) * 0.5f);
        while (I * (I + 1) / 2 > p) I--;
        while ((I + 1) * (I + 2) / 2 <= p) I++;
        int J = p - I * (I + 1) / 2;             // J <= I

        f16x8 a[8], bm[8];
        #pragma unroll
        for (int r = 0; r < 8; r++) {
            int ia = I * 8 + r;
            a[r] = *(const f16x8*)&T[ia * 256 + ((J ^ swz(ia)) << 3)];
        }
        #pragma unroll
        for (int r = 0; r < 8; r++) {
            int jb = J * 8 + r;
            bm[r] = *(const f16x8*)&T[jb * 256 + ((I ^ swz(jb)) << 3)];
        }
        float di[8], dj[8];
        #pragma unroll
        for (int k = 0; k < 8; k++) { di[k] = Dv[I * 8 + k]; dj[k] = Dv[J * 8 + k]; }

        f16x8 o[8];                              // nA tile (I,J)
        #pragma unroll
        for (int r = 0; r < 8; r++) {
            #pragma unroll
            for (int k = 0; k < 8; k++) {
                float v = 0.5f * ((float)a[r][k] + (float)bm[k][r]);
                if (I == J && r == k) v += 1.0f;
                o[r][k] = (f16)(v * di[r] * dj[k]);
            }
        }
        // write tile (I,J): rows I*8+r, cols J*8..  (global + LDS in-place)
        #pragma unroll
        for (int r = 0; r < 8; r++) {
            int ia = I * 8 + r;
            *(f16x8*)&Ob[(size_t)ia * N_ + J * 8] = o[r];
            *(f16x8*)&T[ia * 256 + ((J ^ swz(ia)) << 3)] = o[r];
        }
        if (I != J) {                            // mirror tile (J,I) = o^T
            #pragma unroll
            for (int r = 0; r < 8; r++) {
                int jb = J * 8 + r;
                f16x8 om;
                #pragma unroll
                for (int k = 0; k < 8; k++) om[k] = o[k][r];
                *(f16x8*)&Ob[(size_t)jb * N_ + I * 8] = om;
                *(f16x8*)&T[jb * 256 + ((I ^ swz(jb)) << 3)] = om;
            }
        }
    }
    __syncthreads();                             // nA fully resident in T

    // ---- 4. GEMM: H1 = relu(nA @ XW1) ; A from LDS, B direct-global ----
    const int ln15 = lane & 15, quad = lane >> 4;
    const int wm = w >> 1, wn = w & 1;           // 4 m-blocks x 2 n-groups
    f16* Hb = H1 + (size_t)b * (N_ * H_);
    for (int no = 0; no < 4; no++) {
        const int n0 = (wn * 4 + no) * 64;
        f32x4 acc[4][4];
        #pragma unroll
        for (int i = 0; i < 4; i++)
            #pragma unroll
            for (int j = 0; j < 4; j++)
                #pragma unroll
                for (int r = 0; r < 4; r++) acc[i][j][r] = 0.0f;

        for (int kk = 0; kk < 4; kk++) {
            #pragma unroll
            for (int ks = 0; ks < 2; ks++) {
                const int g = kk * 8 + ks * 4 + quad;      // 16B k-chunk 0..31
                f16x8 aF[4], bF[4];
                #pragma unroll
                for (int t = 0; t < 4; t++) {
                    int i = wm * 64 + t * 16 + ln15;       // nA row
                    aF[t] = *(const f16x8*)&T[i * 256 + ((g ^ swz(i)) << 3)];
                }
                #pragma unroll
                for (int t = 0; t < 4; t++) {
                    int h = n0 + t * 16 + ln15;            // XW1t row
                    bF[t] = *(const f16x8*)&XW1t[(size_t)h * 256 + g * 8];
                }
                #pragma unroll
                for (int mt = 0; mt < 4; mt++)
                    #pragma unroll
                    for (int nt = 0; nt < 4; nt++)
                        acc[mt][nt] = __builtin_amdgcn_mfma_f32_16x16x32_f16(aF[mt], bF[nt], acc[mt][nt], 0, 0, 0);
            }
        }
        #pragma unroll
        for (int mt = 0; mt < 4; mt++) {
            int node = wm * 64 + mt * 16 + quad * 4;
            #pragma unroll
            for (int nt = 0; nt < 4; nt++) {
                int h = n0 + nt * 16 + ln15;
                #pragma unroll
                for (int rr = 0; rr < 4; rr++) {
                    float v = acc[mt][nt][rr];
                    v = v > 0.f ? v : 0.f;
                    Hb[(size_t)(node + rr) * H_ + h] = (f16)v;
                }
            }
        }
    }
}

// ---------------------------------------------------------------------------
// k_prep: fused weight preprocessing (must run BEFORE k_fsum now).
__global__ __launch_bounds__(256) void k_prep(const float* __restrict__ ne,
                                              const float* __restrict__ w1,
                                              const float* __restrict__ b1,
                                              const float* __restrict__ w2,
                                              const float* __restrict__ w3,
                                              f16* __restrict__ XW1t,
                                              f16* __restrict__ w2t,
                                              f16* __restrict__ w3t) {
    int bid = blockIdx.x;
    if (bid < 512) {
        int h = bid, node = threadIdx.x;
        float s = b1[h];
        #pragma unroll 8
        for (int k = 0; k < F_; k++) s += ne[node * F_ + k] * w1[k * H_ + h];
        XW1t[h * N_ + node] = (f16)s;
    } else {
        int idx4 = bid - 512;
        int which = idx4 >> 10;
        const float* src = which ? w3 : w2;
        f16* dst = which ? w3t : w2t;
        int idx = (idx4 & 1023) * 256 + threadIdx.x;
        int k = idx >> 9, n = idx & 511;
        dst[n * H_ + k] = (f16)src[k * H_ + n];
    }
}

// ---------------------------------------------------------------------------
// k_fused (round-8 proven, 16 waves, counted-vmcnt). Wave tile 64x32.
// REDUCE=0: write Hout[b][node][512]. REDUCE=1: node-sum -> gp[b][512].
template <int REDUCE>
__global__ __launch_bounds__(1024, 4) void k_fused(const f16* __restrict__ Hin,
                                                   const f16* __restrict__ Wt,
                                                   const float* __restrict__ bias,
                                                   const f16* __restrict__ nA,
                                                   f16* __restrict__ Hout,
                                                   float* __restrict__ gp) {
    __shared__ f16 As[2][16384];   // 2 x (256 rows x 64 f16) = 64 KB
    __shared__ f16 WU[32768];      // stage1: Ws[2][8192]; stage2: U_t 128x256

    const int tid  = threadIdx.x;
    const int lane = tid & 63, wave = tid >> 6;      // wave 0..15
    const int ln15 = lane & 15, quad = lane >> 4;
    const int wm = wave >> 2, wn = wave & 3;         // 4 m-quadrants, 4 n-slices(32)

    const int lin = blockIdx.x;
    const int xcd = lin & 7, p = lin >> 3;
    const int grp = xcd * 128 + p;                   // 0..1023
    const int b = grp >> 2, hc = grp & 3;

    const f16* Hb = Hin + (size_t)b * (N_ * H_);
    const f16* Ab = nA + (size_t)b * (N_ * N_);
    const f16* Wc = Wt + (size_t)(hc * 128) * H_;

    const int lr = lane >> 3;
    const int kc = (lane & 7) ^ lr;                  // swizzled global 16B k-chunk

    auto stage1 = [&](int buf, int kt) {             // 3 gload_lds per wave
        #pragma unroll
        for (int c = 0; c < 2; c++) {                // Hin: 32 chunks / 16 waves
            int chunk = wave * 2 + c;
            int row = chunk * 8 + lr;                // 0..255
            __builtin_amdgcn_global_load_lds(
                (__attribute__((address_space(1))) void*)(Hb + (size_t)row * H_ + kt * 64 + kc * 8),
                (__attribute__((address_space(3))) void*)(&As[buf][chunk * 512]), 16, 0, 0);
        }
        {                                            // Wt: 16 chunks / 16 waves
            int chunk = wave;
            int row = chunk * 8 + lr;                // 0..127
            __builtin_amdgcn_global_load_lds(
                (__attribute__((address_space(1))) void*)(Wc + (size_t)row * H_ + kt * 64 + kc * 8),
                (__attribute__((address_space(3))) void*)(&WU[buf * 8192 + chunk * 512]), 16, 0, 0);
        }
    };
    auto stage2 = [&](int buf, int jt) {             // 2 gload_lds per wave
        #pragma unroll
        for (int c = 0; c < 2; c++) {                // nA: 32 chunks / 16 waves
            int chunk = wave * 2 + c;
            int row = chunk * 8 + lr;
            __builtin_amdgcn_global_load_lds(
                (__attribute__((address_space(1))) void*)(Ab + (size_t)row * N_ + jt * 64 + kc * 8),
                (__attribute__((address_space(3))) void*)(&As[buf][chunk * 512]), 16, 0, 0);
        }
    };

    f32x4 acc[4][2];
    #pragma unroll
    for (int i = 0; i < 4; i++)
        #pragma unroll
        for (int j = 0; j < 2; j++)
            #pragma unroll
            for (int r = 0; r < 4; r++) acc[i][j][r] = 0.0f;

    // ---------------- stage 1: U = Hin @ Wc^T + bias --------------------
    stage1(0, 0);                                    // 3 in flight
    for (int kt = 0; kt < 8; ++kt) {
        const int buf = kt & 1;
        if (kt < 7) {
            stage1(buf ^ 1, kt + 1);                 // +3 (6 in flight)
            BAR_ACQ(3);
        } else {
            stage2(0, 0);                            // +2: prefetch first nA tile
            BAR_ACQ(2);
        }
        __builtin_amdgcn_s_setprio(1);
        #pragma unroll
        for (int ks = 0; ks < 2; ks++) {
            const int rkc = ks * 4 + quad;
            f16x8 aF[4], bF[2];
            #pragma unroll
            for (int t = 0; t < 4; t++) {
                int ra = wm * 64 + t * 16 + ln15;
                aF[t] = *(const f16x8*)&As[buf][(ra * 8 + (rkc ^ (ra & 7))) * 8];
            }
            #pragma unroll
            for (int t = 0; t < 2; t++) {
                int rb = wn * 32 + t * 16 + ln15;
                bF[t] = *(const f16x8*)&WU[buf * 8192 + (rb * 8 + (rkc ^ (rb & 7))) * 8];
            }
            #pragma unroll
            for (int mt = 0; mt < 4; mt++)
                #pragma unroll
                for (int nt = 0; nt < 2; nt++)
                    acc[mt][nt] = __builtin_amdgcn_mfma_f32_16x16x32_f16(aF[mt], bF[nt], acc[mt][nt], 0, 0, 0);
        }
        __builtin_amdgcn_s_setprio(0);
        BAR_REL();
    }

    // epilogue 1: acc(+bias) -> U_t[h][j] in WU, chunk-swizzled.
    #pragma unroll
    for (int nt = 0; nt < 2; nt++) {
        int hl = wn * 32 + nt * 16 + ln15;
        float bv = bias[hc * 128 + hl];
        #pragma unroll
        for (int mt = 0; mt < 4; mt++) {
            int j = wm * 64 + mt * 16 + quad * 4;
            int slot = (j >> 3) ^ (hl & 7);
            f16x4 v;
            #pragma unroll
            for (int rr = 0; rr < 4; rr++) v[rr] = (f16)(acc[mt][nt][rr] + bv);
            *(f16x4*)&WU[hl * 256 + slot * 8 + (j & 7)] = v;
        }
    }
    asm volatile("s_waitcnt lgkmcnt(0)" ::: "memory");
    __builtin_amdgcn_s_barrier();
    __builtin_amdgcn_sched_barrier(0);

    // ---------------- stage 2: relu(nA @ U) -----------------------------
    #pragma unroll
    for (int i = 0; i < 4; i++)
        #pragma unroll
        for (int j = 0; j < 2; j++)
            #pragma unroll
            for (int r = 0; r < 4; r++) acc[i][j][r] = 0.0f;

    for (int jt = 0; jt < 4; ++jt) {
        const int buf = jt & 1;
        if (jt < 3) {
            stage2(buf ^ 1, jt + 1);                 // +2 (4 in flight)
            BAR_ACQ(2);
        } else {
            BAR_ACQ(0);
        }
        __builtin_amdgcn_s_setprio(1);
        #pragma unroll
        for (int ks = 0; ks < 2; ks++) {
            const int rkc = ks * 4 + quad;
            f16x8 aF[4], bF[2];
            #pragma unroll
            for (int t = 0; t < 4; t++) {
                int ra = wm * 64 + t * 16 + ln15;
                aF[t] = *(const f16x8*)&As[buf][(ra * 8 + (rkc ^ (ra & 7))) * 8];
            }
            #pragma unroll
            for (int t = 0; t < 2; t++) {
                int rb = wn * 32 + t * 16 + ln15;
                int g = jt * 8 + rkc;
                bF[t] = *(const f16x8*)&WU[rb * 256 + ((g ^ (rb & 7)) * 8)];
            }
            #pragma unroll
            for (int mt = 0; mt < 4; mt++)
                #pragma unroll
                for (int nt = 0; nt < 2; nt++)
                    acc[mt][nt] = __builtin_amdgcn_mfma_f32_16x16x32_f16(aF[mt], bF[nt], acc[mt][nt], 0, 0, 0);
        }
        __builtin_amdgcn_s_setprio(0);
        BAR_REL();
    }

    if (REDUCE == 0) {
        f16* Ob = Hout + (size_t)b * (N_ * H_);
        #pragma unroll
        for (int mt = 0; mt < 4; mt++) {
            int node = wm * 64 + mt * 16 + quad * 4;
            #pragma unroll
            for (int nt = 0; nt < 2; nt++) {
                int hg = hc * 128 + wn * 32 + nt * 16 + ln15;
                #pragma unroll
                for (int rr = 0; rr < 4; rr++) {
                    float v = acc[mt][nt][rr];
                    v = v > 0.f ? v : 0.f;
                    Ob[(size_t)(node + rr) * H_ + hg] = (f16)v;
                }
            }
        }
    } else {
        float part[2];
        #pragma unroll
        for (int nt = 0; nt < 2; nt++) {
            float s = 0.f;
            #pragma unroll
            for (int mt = 0; mt < 4; mt++)
                #pragma unroll
                for (int rr = 0; rr < 4; rr++) {
                    float v = acc[mt][nt][rr];
                    s += (v > 0.f ? v : 0.f);
                }
            s += __shfl_down(s, 32, 64);
            s += __shfl_down(s, 16, 64);
            part[nt] = s;                            // valid on quad==0 lanes
        }
        __syncthreads();
        float* red = (float*)&As[0][0];              // 16 waves x 32 cols
        if (quad == 0) {
            #pragma unroll
            for (int nt = 0; nt < 2; nt++)
                red[wave * 32 + nt * 16 + ln15] = part[nt];
        }
        __syncthreads();
        if (tid < 128) {
            int wnl = tid >> 5, cl = tid & 31;
            float g = red[(0 * 4 + wnl) * 32 + cl] + red[(1 * 4 + wnl) * 32 + cl]
                    + red[(2 * 4 + wnl) * 32 + cl] + red[(3 * 4 + wnl) * 32 + cl];
            gp[(size_t)b * H_ + hc * 128 + tid] = g;
        }
    }
}

// ---------------------------------------------------------------------------
// k_logits: logits[b] = (gp[b]/N) @ fcw + fcb.  grid B_ x 256.
__global__ __launch_bounds__(256) void k_logits(const float* __restrict__ gp,
                                                const float* __restrict__ fcw,
                                                const float* __restrict__ fcb,
                                                float* __restrict__ out) {
    int b = blockIdx.x, tid = threadIdx.x;
    const float* g = gp + (size_t)b * H_;
    float g0 = g[tid];
    float g1 = g[tid + 256];
    float p0 = g0 * fcw[tid * 2 + 0] + g1 * fcw[(tid + 256) * 2 + 0];
    float p1 = g0 * fcw[tid * 2 + 1] + g1 * fcw[(tid + 256) * 2 + 1];
    for (int off = 32; off; off >>= 1) {
        p0 += __shfl_down(p0, off, 64);
        p1 += __shfl_down(p1, off, 64);
    }
    __shared__ float r0[4], r1[4];
    int lane = tid & 63, w = tid >> 6;
    if (lane == 0) { r0[w] = p0; r1[w] = p1; }
    __syncthreads();
    const float inv = 1.0f / N_;
    if (tid == 0) out[b * 2 + 0] = (r0[0] + r0[1] + r0[2] + r0[3]) * inv + fcb[0];
    if (tid == 1) out[b * 2 + 1] = (r1[0] + r1[1] + r1[2] + r1[3]) * inv + fcb[1];
}

// ---------------------------------------------------------------------------
extern "C" void kernel_launch(void* const* d_in, const int* in_sizes, int n_in,
                              void* d_out, int out_size, void* d_ws, size_t ws_size,
                              hipStream_t stream) {
    const float* z   = (const float*)d_in[0];
    const float* ne  = (const float*)d_in[1];
    const float* w1  = (const float*)d_in[2];
    const float* b1  = (const float*)d_in[3];
    const float* w2  = (const float*)d_in[4];
    const float* b2  = (const float*)d_in[5];
    const float* w3  = (const float*)d_in[6];
    const float* b3  = (const float*)d_in[7];
    const float* fcw = (const float*)d_in[8];
    const float* fcb = (const float*)d_in[9];
    float* out = (float*)d_out;

    char* ws = (char*)d_ws;
    f16*   T     = (f16*)(ws + 0);            // 67,108,864 (T2/T3 intermediate)
    f16*   nA    = (f16*)(ws + 67108864);     // 33,554,432
    f16*   Hh    = (f16*)(ws + 100663296);    // 67,108,864 (H1)
    float* gpart = (float*)(ws + 100663296);  //    524,288 (alias Hh, H1 dead after F2)
    f16*   XW1t  = (f16*)(ws + 167772160);    //    262,144
    f16*   w2t   = (f16*)(ws + 168034304);    //    524,288
    f16*   w3t   = (f16*)(ws + 168558592);    //    524,288

    // weights first: k_fsum's fused L1 GEMM needs XW1t
    k_prep<<<2560, 256, 0, stream>>>(ne, w1, b1, w2, w3, XW1t, w2t, w3t);
    // z -> nA (HBM) + nA in LDS -> H1 = relu(nA @ XW1) fused (k_gemm removed)
    k_fsum<<<256, 512, 0, stream>>>(z, XW1t, nA, Hh);

    // Layer 2 fused: H2 = relu(nA @ (H1 @ w2 + b2))
    k_fused<0><<<1024, 1024, 0, stream>>>(Hh, w2t, b2, nA, T, nullptr);
    // Layer 3 fused + readout: gp[b][h] = sum_i relu(nA @ (H2 @ w3 + b3))[i][h]
    k_fused<1><<<1024, 1024, 0, stream>>>(T, w3t, b3, nA, nullptr, gpart);

    k_logits<<<B_, 256, 0, stream>>>(gpart, fcw, fcb, out);
}

// Round 10
// 301.905 us; speedup vs baseline: 1.2686x; 1.2686x over previous
//
#include <hip/hip_runtime.h>
#include <stdint.h>

#define B_ 256
#define N_ 256
#define F_ 64
#define H_ 512

typedef _Float16 f16;
typedef _Float16 f16x8 __attribute__((ext_vector_type(8)));
typedef _Float16 f16x4 __attribute__((ext_vector_type(4)));
typedef _Float16 f16x2 __attribute__((ext_vector_type(2)));
typedef float    f32x4 __attribute__((ext_vector_type(4)));

__device__ __forceinline__ float sigmoidf_(float x) {
    return 1.0f / (1.0f + __expf(-x));
}

// Counted-vmcnt barrier pair (T3/T4 pattern, round-5/8 proven):
#define BAR_ACQ(N) do { \
    asm volatile("s_waitcnt vmcnt(" #N ")" ::: "memory"); \
    __builtin_amdgcn_s_barrier(); \
    __builtin_amdgcn_sched_barrier(0); } while (0)
#define BAR_REL() do { \
    __builtin_amdgcn_sched_barrier(0); \
    __builtin_amdgcn_s_barrier(); } while (0)

// ---------------------------------------------------------------------------
// k_fsum v2 (round-8 proven): fused sigmoid + symmetrize + degree-normalize,
// one block/batch, bijective 16B-chunk swizzled T, all-b128 LDS accesses.
__global__ __launch_bounds__(512) void k_fsum(const float* __restrict__ z,
                                              f16* __restrict__ nA) {
    __shared__ f16 T[256 * 256];         // 128 KB
    __shared__ float cpart[8][256];      // 8 KB
    __shared__ float rpart[256][2];      // 2 KB
    __shared__ float Dv[256];            // 1 KB

    const int b = blockIdx.x;
    const int tid = threadIdx.x, lane = tid & 63, w = tid >> 6;
    const float* zb = z + (size_t)b * (N_ * N_);

    auto swz = [](int i) { return (i & 31) ^ (i >> 5); };

    float colacc[4] = {0.f, 0.f, 0.f, 0.f};
    const int ch = lane >> 1, half = lane & 1;
    for (int r = 0; r < 32; r++) {
        int i = w * 32 + r;
        float4 v = *(const float4*)(zb + (size_t)i * N_ + lane * 4);
        float s0 = sigmoidf_(v.x), s1 = sigmoidf_(v.y),
              s2 = sigmoidf_(v.z), s3 = sigmoidf_(v.w);
        f16x4 sv = { (f16)s0, (f16)s1, (f16)s2, (f16)s3 };
        *(f16x4*)&T[i * 256 + ((ch ^ swz(i)) << 3) + half * 4] = sv;
        colacc[0] += s0; colacc[1] += s1; colacc[2] += s2; colacc[3] += s3;
    }
    #pragma unroll
    for (int k = 0; k < 4; k++) cpart[w][lane * 4 + k] = colacc[k];
    __syncthreads();

    {
        int i = tid >> 1, h = tid & 1;
        float s = 0.f;
        #pragma unroll
        for (int c = 0; c < 16; c++) {
            int cc = h * 16 + c;
            f16x8 v = *(const f16x8*)&T[i * 256 + ((cc ^ swz(i)) << 3)];
            #pragma unroll
            for (int k = 0; k < 8; k++) s += (float)v[k];
        }
        rpart[i][h] = s;
    }
    __syncthreads();

    if (tid < 256) {
        float cs = 0.f;
        #pragma unroll
        for (int ww = 0; ww < 8; ww++) cs += cpart[ww][tid];
        float rs = rpart[tid][0] + rpart[tid][1];
        Dv[tid] = rsqrtf(1.0f + 1e-6f + 0.5f * (rs + cs));
    }
    __syncthreads();

    f16* Ob = nA + (size_t)b * (N_ * N_);
    #pragma unroll
    for (int tt = 0; tt < 2; tt++) {
        int tile = tt * 512 + tid;
        int I = tile >> 5, J = tile & 31;
        f16x8 a[8], bm[8];
        #pragma unroll
        for (int r = 0; r < 8; r++) {
            int ia = I * 8 + r;
            a[r] = *(const f16x8*)&T[ia * 256 + ((J ^ swz(ia)) << 3)];
        }
        #pragma unroll
        for (int r = 0; r < 8; r++) {
            int jb = J * 8 + r;
            bm[r] = *(const f16x8*)&T[jb * 256 + ((I ^ swz(jb)) << 3)];
        }
        float dj[8];
        #pragma unroll
        for (int k = 0; k < 8; k++) dj[k] = Dv[J * 8 + k];
        #pragma unroll
        for (int r = 0; r < 8; r++) {
            float di = Dv[I * 8 + r];
            f16x8 o;
            #pragma unroll
            for (int k = 0; k < 8; k++) {
                float v = 0.5f * ((float)a[r][k] + (float)bm[k][r]);
                if (I * 8 + r == J * 8 + k) v += 1.0f;
                o[k] = (f16)(v * di * dj[k]);
            }
            *(f16x8*)&Ob[(size_t)(I * 8 + r) * N_ + J * 8] = o;
        }
    }
}

// ---------------------------------------------------------------------------
// k_prep: fused weight preprocessing.
__global__ __launch_bounds__(256) void k_prep(const float* __restrict__ ne,
                                              const float* __restrict__ w1,
                                              const float* __restrict__ b1,
                                              const float* __restrict__ w2,
                                              const float* __restrict__ w3,
                                              f16* __restrict__ XW1t,
                                              f16* __restrict__ w2t,
                                              f16* __restrict__ w3t) {
    int bid = blockIdx.x;
    if (bid < 512) {
        int h = bid, node = threadIdx.x;
        float s = b1[h];
        #pragma unroll 8
        for (int k = 0; k < F_; k++) s += ne[node * F_ + k] * w1[k * H_ + h];
        XW1t[h * N_ + node] = (f16)s;
    } else {
        int idx4 = bid - 512;
        int which = idx4 >> 10;
        const float* src = which ? w3 : w2;
        f16* dst = which ? w3t : w2t;
        int idx = (idx4 & 1023) * 256 + threadIdx.x;
        int k = idx >> 9, n = idx & 511;
        dst[n * H_ + k] = (f16)src[k * H_ + n];
    }
}

// ---------------------------------------------------------------------------
// k_gemm2: layer-1 GEMM H1 = relu(nA @ XW1), transplant of the round-8
// k_fused stage-1 skeleton (16 waves, counted-vmcnt, dbuf, 3 gloads/wave).
// One block per (b, 128-node half). Operand roles: "Hin slot" = XW1t tile
// (256 h-rows x 64k), "W slot" = nA tile (128 node-rows x 64k). 8 unified
// steps = 2 h-passes x 4 k-steps; pass-0 epilogue mid-loop. C layout makes
// h the in-thread-contiguous axis -> f16x4 H1 stores.
__global__ __launch_bounds__(1024, 4) void k_gemm2(const f16* __restrict__ nA,
                                                   const f16* __restrict__ XW1t,
                                                   f16* __restrict__ H1) {
    __shared__ f16 Bs[2][16384];   // XW1t tile dbuf: 256 rows x 64 f16 (64 KB)
    __shared__ f16 Am[2][8192];    // nA tile dbuf: 128 rows x 64 f16 (32 KB)

    const int tid = threadIdx.x;
    const int lane = tid & 63, wave = tid >> 6;      // 16 waves
    const int ln15 = lane & 15, quad = lane >> 4;
    const int wm = wave >> 2, wn = wave & 3;         // wm: 4 h-quadrants(64), wn: 4 node-slices(32)

    const int lin = blockIdx.x;
    const int xcd = lin & 7, p = lin >> 3;
    const int grp = xcd * 64 + p;                    // 0..511
    const int b = grp >> 1, m_t = grp & 1;
    const int m0 = m_t * 128;

    const f16* Ab = nA + (size_t)b * (N_ * N_);
    f16* Hb = H1 + (size_t)b * (N_ * H_);

    const int lr = lane >> 3;
    const int kc = (lane & 7) ^ lr;                  // swizzled global 16B k-chunk

    // step s: pass=s>>2 (h half), kt=s&3 (k step), buf=s&1. 3 gload_lds/wave.
    auto stage = [&](int s) {
        int pass = (s >> 2) & 1, kt = s & 3, buf = s & 1;
        #pragma unroll
        for (int c = 0; c < 2; c++) {                // XW1t: 32 chunks / 16 waves
            int chunk = wave * 2 + c;
            int row = pass * 256 + chunk * 8 + lr;   // h row
            __builtin_amdgcn_global_load_lds(
                (__attribute__((address_space(1))) void*)(XW1t + (size_t)row * 256 + kt * 64 + kc * 8),
                (__attribute__((address_space(3))) void*)(&Bs[buf][chunk * 512]), 16, 0, 0);
        }
        {                                            // nA: 16 chunks / 16 waves
            int chunk = wave;
            int row = m0 + chunk * 8 + lr;           // node row
            __builtin_amdgcn_global_load_lds(
                (__attribute__((address_space(1))) void*)(Ab + (size_t)row * N_ + kt * 64 + kc * 8),
                (__attribute__((address_space(3))) void*)(&Am[buf][chunk * 512]), 16, 0, 0);
        }
    };

    f32x4 acc[4][2];
    #pragma unroll
    for (int i = 0; i < 4; i++)
        #pragma unroll
        for (int j = 0; j < 2; j++)
            #pragma unroll
            for (int r = 0; r < 4; r++) acc[i][j][r] = 0.0f;

    auto cwrite = [&](int pass) {
        #pragma unroll
        for (int mt = 0; mt < 4; mt++) {
            int h0 = pass * 256 + wm * 64 + mt * 16 + quad * 4;
            #pragma unroll
            for (int nt = 0; nt < 2; nt++) {
                int node = m0 + wn * 32 + nt * 16 + ln15;
                f16x4 v;
                #pragma unroll
                for (int rr = 0; rr < 4; rr++) {
                    float x = acc[mt][nt][rr];
                    v[rr] = (f16)(x > 0.f ? x : 0.f);
                }
                *(f16x4*)&Hb[(size_t)node * H_ + h0] = v;
            }
        }
    };

    stage(0);                                        // 3 in flight
    for (int s = 0; s < 8; ++s) {
        const int buf = s & 1;
        if (s < 7) {
            stage(s + 1);                            // +3 (6 in flight)
            BAR_ACQ(3);                              // oldest 3 (tile s) landed
        } else {
            BAR_ACQ(0);
        }
        __builtin_amdgcn_s_setprio(1);
        #pragma unroll
        for (int ks = 0; ks < 2; ks++) {
            const int rkc = ks * 4 + quad;
            f16x8 aF[4], bF[2];
            #pragma unroll
            for (int t = 0; t < 4; t++) {
                int ra = wm * 64 + t * 16 + ln15;    // XW1t row (h-local)
                aF[t] = *(const f16x8*)&Bs[buf][(ra * 8 + (rkc ^ (ra & 7))) * 8];
            }
            #pragma unroll
            for (int t = 0; t < 2; t++) {
                int rb = wn * 32 + t * 16 + ln15;    // nA row (node-local)
                bF[t] = *(const f16x8*)&Am[buf][(rb * 8 + (rkc ^ (rb & 7))) * 8];
            }
            #pragma unroll
            for (int mt = 0; mt < 4; mt++)
                #pragma unroll
                for (int nt = 0; nt < 2; nt++)
                    acc[mt][nt] = __builtin_amdgcn_mfma_f32_16x16x32_f16(aF[mt], bF[nt], acc[mt][nt], 0, 0, 0);
        }
        __builtin_amdgcn_s_setprio(0);
        if (s == 3) {                                // end of pass 0
            cwrite(0);
            #pragma unroll
            for (int i = 0; i < 4; i++)
                #pragma unroll
                for (int j = 0; j < 2; j++)
                    #pragma unroll
                    for (int r = 0; r < 4; r++) acc[i][j][r] = 0.0f;
        }
        BAR_REL();
    }
    cwrite(1);
}

// ---------------------------------------------------------------------------
// k_fused (round-8 proven, 16 waves, counted-vmcnt). Wave tile 64x32.
// REDUCE=0: write Hout[b][node][512]. REDUCE=1: node-sum -> gp[b][512].
template <int REDUCE>
__global__ __launch_bounds__(1024, 4) void k_fused(const f16* __restrict__ Hin,
                                                   const f16* __restrict__ Wt,
                                                   const float* __restrict__ bias,
                                                   const f16* __restrict__ nA,
                                                   f16* __restrict__ Hout,
                                                   float* __restrict__ gp) {
    __shared__ f16 As[2][16384];   // 2 x (256 rows x 64 f16) = 64 KB
    __shared__ f16 WU[32768];      // stage1: Ws[2][8192]; stage2: U_t 128x256

    const int tid  = threadIdx.x;
    const int lane = tid & 63, wave = tid >> 6;      // wave 0..15
    const int ln15 = lane & 15, quad = lane >> 4;
    const int wm = wave >> 2, wn = wave & 3;         // 4 m-quadrants, 4 n-slices(32)

    const int lin = blockIdx.x;
    const int xcd = lin & 7, p = lin >> 3;
    const int grp = xcd * 128 + p;                   // 0..1023
    const int b = grp >> 2, hc = grp & 3;

    const f16* Hb = Hin + (size_t)b * (N_ * H_);
    const f16* Ab = nA + (size_t)b * (N_ * N_);
    const f16* Wc = Wt + (size_t)(hc * 128) * H_;

    const int lr = lane >> 3;
    const int kc = (lane & 7) ^ lr;                  // swizzled global 16B k-chunk

    auto stage1 = [&](int buf, int kt) {             // 3 gload_lds per wave
        #pragma unroll
        for (int c = 0; c < 2; c++) {                // Hin: 32 chunks / 16 waves
            int chunk = wave * 2 + c;
            int row = chunk * 8 + lr;                // 0..255
            __builtin_amdgcn_global_load_lds(
                (__attribute__((address_space(1))) void*)(Hb + (size_t)row * H_ + kt * 64 + kc * 8),
                (__attribute__((address_space(3))) void*)(&As[buf][chunk * 512]), 16, 0, 0);
        }
        {                                            // Wt: 16 chunks / 16 waves
            int chunk = wave;
            int row = chunk * 8 + lr;                // 0..127
            __builtin_amdgcn_global_load_lds(
                (__attribute__((address_space(1))) void*)(Wc + (size_t)row * H_ + kt * 64 + kc * 8),
                (__attribute__((address_space(3))) void*)(&WU[buf * 8192 + chunk * 512]), 16, 0, 0);
        }
    };
    auto stage2 = [&](int buf, int jt) {             // 2 gload_lds per wave
        #pragma unroll
        for (int c = 0; c < 2; c++) {                // nA: 32 chunks / 16 waves
            int chunk = wave * 2 + c;
            int row = chunk * 8 + lr;
            __builtin_amdgcn_global_load_lds(
                (__attribute__((address_space(1))) void*)(Ab + (size_t)row * N_ + jt * 64 + kc * 8),
                (__attribute__((address_space(3))) void*)(&As[buf][chunk * 512]), 16, 0, 0);
        }
    };

    f32x4 acc[4][2];
    #pragma unroll
    for (int i = 0; i < 4; i++)
        #pragma unroll
        for (int j = 0; j < 2; j++)
            #pragma unroll
            for (int r = 0; r < 4; r++) acc[i][j][r] = 0.0f;

    // ---------------- stage 1: U = Hin @ Wc^T + bias --------------------
    stage1(0, 0);                                    // 3 in flight
    for (int kt = 0; kt < 8; ++kt) {
        const int buf = kt & 1;
        if (kt < 7) {
            stage1(buf ^ 1, kt + 1);                 // +3 (6 in flight)
            BAR_ACQ(3);
        } else {
            stage2(0, 0);                            // +2: prefetch first nA tile
            BAR_ACQ(2);
        }
        __builtin_amdgcn_s_setprio(1);
        #pragma unroll
        for (int ks = 0; ks < 2; ks++) {
            const int rkc = ks * 4 + quad;
            f16x8 aF[4], bF[2];
            #pragma unroll
            for (int t = 0; t < 4; t++) {
                int ra = wm * 64 + t * 16 + ln15;
                aF[t] = *(const f16x8*)&As[buf][(ra * 8 + (rkc ^ (ra & 7))) * 8];
            }
            #pragma unroll
            for (int t = 0; t < 2; t++) {
                int rb = wn * 32 + t * 16 + ln15;
                bF[t] = *(const f16x8*)&WU[buf * 8192 + (rb * 8 + (rkc ^ (rb & 7))) * 8];
            }
            #pragma unroll
            for (int mt = 0; mt < 4; mt++)
                #pragma unroll
                for (int nt = 0; nt < 2; nt++)
                    acc[mt][nt] = __builtin_amdgcn_mfma_f32_16x16x32_f16(aF[mt], bF[nt], acc[mt][nt], 0, 0, 0);
        }
        __builtin_amdgcn_s_setprio(0);
        BAR_REL();
    }

    // epilogue 1: acc(+bias) -> U_t[h][j] in WU, chunk-swizzled.
    #pragma unroll
    for (int nt = 0; nt < 2; nt++) {
        int hl = wn * 32 + nt * 16 + ln15;
        float bv = bias[hc * 128 + hl];
        #pragma unroll
        for (int mt = 0; mt < 4; mt++) {
            int j = wm * 64 + mt * 16 + quad * 4;
            int slot = (j >> 3) ^ (hl & 7);
            f16x4 v;
            #pragma unroll
            for (int rr = 0; rr < 4; rr++) v[rr] = (f16)(acc[mt][nt][rr] + bv);
            *(f16x4*)&WU[hl * 256 + slot * 8 + (j & 7)] = v;
        }
    }
    asm volatile("s_waitcnt lgkmcnt(0)" ::: "memory");
    __builtin_amdgcn_s_barrier();
    __builtin_amdgcn_sched_barrier(0);

    // ---------------- stage 2: relu(nA @ U) -----------------------------
    #pragma unroll
    for (int i = 0; i < 4; i++)
        #pragma unroll
        for (int j = 0; j < 2; j++)
            #pragma unroll
            for (int r = 0; r < 4; r++) acc[i][j][r] = 0.0f;

    for (int jt = 0; jt < 4; ++jt) {
        const int buf = jt & 1;
        if (jt < 3) {
            stage2(buf ^ 1, jt + 1);                 // +2 (4 in flight)
            BAR_ACQ(2);
        } else {
            BAR_ACQ(0);
        }
        __builtin_amdgcn_s_setprio(1);
        #pragma unroll
        for (int ks = 0; ks < 2; ks++) {
            const int rkc = ks * 4 + quad;
            f16x8 aF[4], bF[2];
            #pragma unroll
            for (int t = 0; t < 4; t++) {
                int ra = wm * 64 + t * 16 + ln15;
                aF[t] = *(const f16x8*)&As[buf][(ra * 8 + (rkc ^ (ra & 7))) * 8];
            }
            #pragma unroll
            for (int t = 0; t < 2; t++) {
                int rb = wn * 32 + t * 16 + ln15;
                int g = jt * 8 + rkc;
                bF[t] = *(const f16x8*)&WU[rb * 256 + ((g ^ (rb & 7)) * 8)];
            }
            #pragma unroll
            for (int mt = 0; mt < 4; mt++)
                #pragma unroll
                for (int nt = 0; nt < 2; nt++)
                    acc[mt][nt] = __builtin_amdgcn_mfma_f32_16x16x32_f16(aF[mt], bF[nt], acc[mt][nt], 0, 0, 0);
        }
        __builtin_amdgcn_s_setprio(0);
        BAR_REL();
    }

    if (REDUCE == 0) {
        f16* Ob = Hout + (size_t)b * (N_ * H_);
        #pragma unroll
        for (int mt = 0; mt < 4; mt++) {
            int node = wm * 64 + mt * 16 + quad * 4;
            #pragma unroll
            for (int nt = 0; nt < 2; nt++) {
                int hg = hc * 128 + wn * 32 + nt * 16 + ln15;
                #pragma unroll
                for (int rr = 0; rr < 4; rr++) {
                    float v = acc[mt][nt][rr];
                    v = v > 0.f ? v : 0.f;
                    Ob[(size_t)(node + rr) * H_ + hg] = (f16)v;
                }
            }
        }
    } else {
        float part[2];
        #pragma unroll
        for (int nt = 0; nt < 2; nt++) {
            float s = 0.f;
            #pragma unroll
            for (int mt = 0; mt < 4; mt++)
                #pragma unroll
                for (int rr = 0; rr < 4; rr++) {
                    float v = acc[mt][nt][rr];
                    s += (v > 0.f ? v : 0.f);
                }
            s += __shfl_down(s, 32, 64);
            s += __shfl_down(s, 16, 64);
            part[nt] = s;                            // valid on quad==0 lanes
        }
        __syncthreads();
        float* red = (float*)&As[0][0];              // 16 waves x 32 cols
        if (quad == 0) {
            #pragma unroll
            for (int nt = 0; nt < 2; nt++)
                red[wave * 32 + nt * 16 + ln15] = part[nt];
        }
        __syncthreads();
        if (tid < 128) {
            int wnl = tid >> 5, cl = tid & 31;
            float g = red[(0 * 4 + wnl) * 32 + cl] + red[(1 * 4 + wnl) * 32 + cl]
                    + red[(2 * 4 + wnl) * 32 + cl] + red[(3 * 4 + wnl) * 32 + cl];
            gp[(size_t)b * H_ + hc * 128 + tid] = g;
        }
    }
}

// ---------------------------------------------------------------------------
// k_logits: logits[b] = (gp[b]/N) @ fcw + fcb.  grid B_ x 256.
__global__ __launch_bounds__(256) void k_logits(const float* __restrict__ gp,
                                                const float* __restrict__ fcw,
                                                const float* __restrict__ fcb,
                                                float* __restrict__ out) {
    int b = blockIdx.x, tid = threadIdx.x;
    const float* g = gp + (size_t)b * H_;
    float g0 = g[tid];
    float g1 = g[tid + 256];
    float p0 = g0 * fcw[tid * 2 + 0] + g1 * fcw[(tid + 256) * 2 + 0];
    float p1 = g0 * fcw[tid * 2 + 1] + g1 * fcw[(tid + 256) * 2 + 1];
    for (int off = 32; off; off >>= 1) {
        p0 += __shfl_down(p0, off, 64);
        p1 += __shfl_down(p1, off, 64);
    }
    __shared__ float r0[4], r1[4];
    int lane = tid & 63, w = tid >> 6;
    if (lane == 0) { r0[w] = p0; r1[w] = p1; }
    __syncthreads();
    const float inv = 1.0f / N_;
    if (tid == 0) out[b * 2 + 0] = (r0[0] + r0[1] + r0[2] + r0[3]) * inv + fcb[0];
    if (tid == 1) out[b * 2 + 1] = (r1[0] + r1[1] + r1[2] + r1[3]) * inv + fcb[1];
}

// ---------------------------------------------------------------------------
extern "C" void kernel_launch(void* const* d_in, const int* in_sizes, int n_in,
                              void* d_out, int out_size, void* d_ws, size_t ws_size,
                              hipStream_t stream) {
    const float* z   = (const float*)d_in[0];
    const float* ne  = (const float*)d_in[1];
    const float* w1  = (const float*)d_in[2];
    const float* b1  = (const float*)d_in[3];
    const float* w2  = (const float*)d_in[4];
    const float* b2  = (const float*)d_in[5];
    const float* w3  = (const float*)d_in[6];
    const float* b3  = (const float*)d_in[7];
    const float* fcw = (const float*)d_in[8];
    const float* fcb = (const float*)d_in[9];
    float* out = (float*)d_out;

    char* ws = (char*)d_ws;
    f16*   T     = (f16*)(ws + 0);            // 67,108,864 (T2/T3 intermediate)
    f16*   nA    = (f16*)(ws + 67108864);     // 33,554,432
    f16*   Hh    = (f16*)(ws + 100663296);    // 67,108,864 (H1)
    float* gpart = (float*)(ws + 100663296);  //    524,288 (alias Hh, H1 dead after F2)
    f16*   XW1t  = (f16*)(ws + 167772160);    //    262,144
    f16*   w2t   = (f16*)(ws + 168034304);    //    524,288
    f16*   w3t   = (f16*)(ws + 168558592);    //    524,288

    // Fused sigmoid/symmetrize/normalize: z -> nA directly (S never hits HBM)
    k_fsum<<<256, 512, 0, stream>>>(z, nA);
    k_prep<<<2560, 256, 0, stream>>>(ne, w1, b1, w2, w3, XW1t, w2t, w3t);

    // Layer 1: H1 = relu(nA @ XW1)  (16-wave counted-vmcnt transplant)
    k_gemm2<<<512, 1024, 0, stream>>>(nA, XW1t, Hh);
    // Layer 2 fused: H2 = relu(nA @ (H1 @ w2 + b2))
    k_fused<0><<<1024, 1024, 0, stream>>>(Hh, w2t, b2, nA, T, nullptr);
    // Layer 3 fused + readout: gp[b][h] = sum_i relu(nA @ (H2 @ w3 + b3))[i][h]
    k_fused<1><<<1024, 1024, 0, stream>>>(T, w3t, b3, nA, nullptr, gpart);

    k_logits<<<B_, 256, 0, stream>>>(gpart, fcw, fcb, out);
}

// Round 11
// 283.290 us; speedup vs baseline: 1.3519x; 1.0657x over previous
//
#include <hip/hip_runtime.h>
#include <stdint.h>

#define B_ 256
#define N_ 256
#define F_ 64
#define H_ 512

typedef _Float16 f16;
typedef _Float16 f16x8 __attribute__((ext_vector_type(8)));
typedef _Float16 f16x4 __attribute__((ext_vector_type(4)));
typedef _Float16 f16x2 __attribute__((ext_vector_type(2)));
typedef float    f32x4 __attribute__((ext_vector_type(4)));

__device__ __forceinline__ float sigmoidf_(float x) {
    return 1.0f / (1.0f + __expf(-x));
}

// Counted-vmcnt barrier pair (T3/T4 pattern, round-5/8 proven):
#define BAR_ACQ(N) do { \
    asm volatile("s_waitcnt vmcnt(" #N ")" ::: "memory"); \
    __builtin_amdgcn_s_barrier(); \
    __builtin_amdgcn_sched_barrier(0); } while (0)
#define BAR_REL() do { \
    __builtin_amdgcn_sched_barrier(0); \
    __builtin_amdgcn_s_barrier(); } while (0)

// ---------------------------------------------------------------------------
// k_front: grid-union of three independent front-end jobs (1024 thr/block):
//  bid [0,256):   fsum for batch b=bid -- sigmoid+symmetrize+normalize -> nA.
//                 16 waves (vs 8 in round-8 version): 2x latency hiding.
//  bid [256,384): XW1t[h,node] = ne[node]*w1[:,h]+b1[h]; ne staged transposed
//                 in LDS (fixes stride-256B uncoalesced reads).
//  bid [384,512): w2/w3 -> f16 transpose via 64x64 LDS tiles (fixes 2B
//                 stride-1KB scattered stores -> coalesced f16x8).
// LDS: T 128KB + cpart 16KB + rpart 4KB + Dv 1KB = 149KB (prep branches
// alias into T). 1 block/CU.
__global__ __launch_bounds__(1024, 4) void k_front(const float* __restrict__ z,
                                                   const float* __restrict__ ne,
                                                   const float* __restrict__ w1,
                                                   const float* __restrict__ b1,
                                                   const float* __restrict__ w2,
                                                   const float* __restrict__ w3,
                                                   f16* __restrict__ nA,
                                                   f16* __restrict__ XW1t,
                                                   f16* __restrict__ w2t,
                                                   f16* __restrict__ w3t) {
    __shared__ f16 T[256 * 256];         // 128 KB
    __shared__ float cpart[16][256];     // 16 KB
    __shared__ float rpart[256][4];      // 4 KB
    __shared__ float Dv[256];            // 1 KB

    const int bid = blockIdx.x, tid = threadIdx.x;
    auto swz = [](int i) { return (i & 31) ^ (i >> 5); };

    if (bid < 256) {
        // ---------------- fsum (round-8 logic, 16 waves) ----------------
        const int lane = tid & 63, w = tid >> 6;     // 16 waves, 16 rows each
        const float* zb = z + (size_t)bid * (N_ * N_);

        float colacc[4] = {0.f, 0.f, 0.f, 0.f};
        const int ch = lane >> 1, half = lane & 1;
        for (int r = 0; r < 16; r++) {
            int i = w * 16 + r;
            float4 v = *(const float4*)(zb + (size_t)i * N_ + lane * 4);
            float s0 = sigmoidf_(v.x), s1 = sigmoidf_(v.y),
                  s2 = sigmoidf_(v.z), s3 = sigmoidf_(v.w);
            f16x4 sv = { (f16)s0, (f16)s1, (f16)s2, (f16)s3 };
            *(f16x4*)&T[i * 256 + ((ch ^ swz(i)) << 3) + half * 4] = sv;
            colacc[0] += s0; colacc[1] += s1; colacc[2] += s2; colacc[3] += s3;
        }
        #pragma unroll
        for (int k = 0; k < 4; k++) cpart[w][lane * 4 + k] = colacc[k];
        __syncthreads();

        // rowsum: 4 threads/row, 8 chunks each
        {
            int i = tid >> 2, q = tid & 3;
            float s = 0.f;
            #pragma unroll
            for (int c = 0; c < 8; c++) {
                int cc = q * 8 + c;
                f16x8 v = *(const f16x8*)&T[i * 256 + ((cc ^ swz(i)) << 3)];
                #pragma unroll
                for (int k = 0; k < 8; k++) s += (float)v[k];
            }
            rpart[i][q] = s;
        }
        __syncthreads();

        if (tid < 256) {
            float cs = 0.f;
            #pragma unroll
            for (int ww = 0; ww < 16; ww++) cs += cpart[ww][tid];
            float rs = rpart[tid][0] + rpart[tid][1] + rpart[tid][2] + rpart[tid][3];
            Dv[tid] = rsqrtf(1.0f + 1e-6f + 0.5f * (rs + cs));
        }
        __syncthreads();

        // emit: exactly one 8x8 tile per thread (1024 tiles)
        f16* Ob = nA + (size_t)bid * (N_ * N_);
        int I = tid >> 5, J = tid & 31;
        f16x8 bm[8];
        #pragma unroll
        for (int r = 0; r < 8; r++) {
            int jb = J * 8 + r;
            bm[r] = *(const f16x8*)&T[jb * 256 + ((I ^ swz(jb)) << 3)];
        }
        float dj[8];
        #pragma unroll
        for (int k = 0; k < 8; k++) dj[k] = Dv[J * 8 + k];
        #pragma unroll
        for (int r = 0; r < 8; r++) {
            int ia = I * 8 + r;
            float di = Dv[ia];
            f16x8 a = *(const f16x8*)&T[ia * 256 + ((J ^ swz(ia)) << 3)];
            f16x8 o;
            #pragma unroll
            for (int k = 0; k < 8; k++) {
                float v = 0.5f * ((float)a[k] + (float)bm[k][r]);
                if (ia == J * 8 + k) v += 1.0f;
                o[k] = (f16)(v * di * dj[k]);
            }
            *(f16x8*)&Ob[(size_t)ia * N_ + J * 8] = o;
        }
    } else if (bid < 384) {
        // ---------------- XW1t: 128 blocks x 1024 = 512h x 256node -------
        float* neL = (float*)T;                      // [64 k][256 node], 64 KB
        #pragma unroll
        for (int it = 0; it < 4; it++) {
            int idx = it * 1024 + tid;               // 0..4095
            int node = idx >> 4, k4 = idx & 15;
            float4 v = *(const float4*)(ne + (size_t)node * F_ + k4 * 4);
            neL[(k4 * 4 + 0) * 256 + node] = v.x;
            neL[(k4 * 4 + 1) * 256 + node] = v.y;
            neL[(k4 * 4 + 2) * 256 + node] = v.z;
            neL[(k4 * 4 + 3) * 256 + node] = v.w;
        }
        __syncthreads();
        int gid = (bid - 256) * 1024 + tid;
        int h = gid >> 8, node = gid & 255;
        float s = b1[h];
        #pragma unroll 8
        for (int k = 0; k < F_; k++) s += neL[k * 256 + node] * w1[k * H_ + h];
        XW1t[h * N_ + node] = (f16)s;
    } else {
        // ---------------- w2/w3 transpose: 64x64 tile per block ----------
        int t = bid - 384;                           // 0..127
        const float* src = (t >= 64) ? w3 : w2;
        f16* dst = (t >= 64) ? w3t : w2t;
        t &= 63;
        const int K0 = (t >> 3) * 64, N0 = (t & 7) * 64;
        f16* ldsT = T;                               // [64 n][72 k], 9.2 KB
        {
            int r = tid >> 4, l16 = tid & 15;        // r: k-row 0..63
            float4 v = *(const float4*)(src + (size_t)(K0 + r) * H_ + N0 + l16 * 4);
            ldsT[(l16 * 4 + 0) * 72 + r] = (f16)v.x;
            ldsT[(l16 * 4 + 1) * 72 + r] = (f16)v.y;
            ldsT[(l16 * 4 + 2) * 72 + r] = (f16)v.z;
            ldsT[(l16 * 4 + 3) * 72 + r] = (f16)v.w;
        }
        __syncthreads();
        if (tid < 512) {
            int n_l = tid >> 3, c8 = tid & 7;
            f16x8 o = *(const f16x8*)&ldsT[n_l * 72 + c8 * 8];   // 144B rows: 16B-aligned
            *(f16x8*)&dst[(size_t)(N0 + n_l) * H_ + K0 + c8 * 8] = o;
        }
    }
}

// ---------------------------------------------------------------------------
// k_gemm2 (round-10 proven): layer-1 GEMM H1 = relu(nA @ XW1), 16-wave
// counted-vmcnt transplant of the k_fused stage-1 skeleton.
__global__ __launch_bounds__(1024, 4) void k_gemm2(const f16* __restrict__ nA,
                                                   const f16* __restrict__ XW1t,
                                                   f16* __restrict__ H1) {
    __shared__ f16 Bs[2][16384];   // XW1t tile dbuf: 256 rows x 64 f16 (64 KB)
    __shared__ f16 Am[2][8192];    // nA tile dbuf: 128 rows x 64 f16 (32 KB)

    const int tid = threadIdx.x;
    const int lane = tid & 63, wave = tid >> 6;      // 16 waves
    const int ln15 = lane & 15, quad = lane >> 4;
    const int wm = wave >> 2, wn = wave & 3;

    const int lin = blockIdx.x;
    const int xcd = lin & 7, p = lin >> 3;
    const int grp = xcd * 64 + p;                    // 0..511
    const int b = grp >> 1, m_t = grp & 1;
    const int m0 = m_t * 128;

    const f16* Ab = nA + (size_t)b * (N_ * N_);
    f16* Hb = H1 + (size_t)b * (N_ * H_);

    const int lr = lane >> 3;
    const int kc = (lane & 7) ^ lr;

    auto stage = [&](int s) {
        int pass = (s >> 2) & 1, kt = s & 3, buf = s & 1;
        #pragma unroll
        for (int c = 0; c < 2; c++) {
            int chunk = wave * 2 + c;
            int row = pass * 256 + chunk * 8 + lr;
            __builtin_amdgcn_global_load_lds(
                (__attribute__((address_space(1))) void*)(XW1t + (size_t)row * 256 + kt * 64 + kc * 8),
                (__attribute__((address_space(3))) void*)(&Bs[buf][chunk * 512]), 16, 0, 0);
        }
        {
            int chunk = wave;
            int row = m0 + chunk * 8 + lr;
            __builtin_amdgcn_global_load_lds(
                (__attribute__((address_space(1))) void*)(Ab + (size_t)row * N_ + kt * 64 + kc * 8),
                (__attribute__((address_space(3))) void*)(&Am[buf][chunk * 512]), 16, 0, 0);
        }
    };

    f32x4 acc[4][2];
    #pragma unroll
    for (int i = 0; i < 4; i++)
        #pragma unroll
        for (int j = 0; j < 2; j++)
            #pragma unroll
            for (int r = 0; r < 4; r++) acc[i][j][r] = 0.0f;

    auto cwrite = [&](int pass) {
        #pragma unroll
        for (int mt = 0; mt < 4; mt++) {
            int h0 = pass * 256 + wm * 64 + mt * 16 + quad * 4;
            #pragma unroll
            for (int nt = 0; nt < 2; nt++) {
                int node = m0 + wn * 32 + nt * 16 + ln15;
                f16x4 v;
                #pragma unroll
                for (int rr = 0; rr < 4; rr++) {
                    float x = acc[mt][nt][rr];
                    v[rr] = (f16)(x > 0.f ? x : 0.f);
                }
                *(f16x4*)&Hb[(size_t)node * H_ + h0] = v;
            }
        }
    };

    stage(0);
    for (int s = 0; s < 8; ++s) {
        const int buf = s & 1;
        if (s < 7) {
            stage(s + 1);
            BAR_ACQ(3);
        } else {
            BAR_ACQ(0);
        }
        __builtin_amdgcn_s_setprio(1);
        #pragma unroll
        for (int ks = 0; ks < 2; ks++) {
            const int rkc = ks * 4 + quad;
            f16x8 aF[4], bF[2];
            #pragma unroll
            for (int t = 0; t < 4; t++) {
                int ra = wm * 64 + t * 16 + ln15;
                aF[t] = *(const f16x8*)&Bs[buf][(ra * 8 + (rkc ^ (ra & 7))) * 8];
            }
            #pragma unroll
            for (int t = 0; t < 2; t++) {
                int rb = wn * 32 + t * 16 + ln15;
                bF[t] = *(const f16x8*)&Am[buf][(rb * 8 + (rkc ^ (rb & 7))) * 8];
            }
            #pragma unroll
            for (int mt = 0; mt < 4; mt++)
                #pragma unroll
                for (int nt = 0; nt < 2; nt++)
                    acc[mt][nt] = __builtin_amdgcn_mfma_f32_16x16x32_f16(aF[mt], bF[nt], acc[mt][nt], 0, 0, 0);
        }
        __builtin_amdgcn_s_setprio(0);
        if (s == 3) {
            cwrite(0);
            #pragma unroll
            for (int i = 0; i < 4; i++)
                #pragma unroll
                for (int j = 0; j < 2; j++)
                    #pragma unroll
                    for (int r = 0; r < 4; r++) acc[i][j][r] = 0.0f;
        }
        BAR_REL();
    }
    cwrite(1);
}

// ---------------------------------------------------------------------------
// k_fused (round-8 proven, 16 waves, counted-vmcnt). Wave tile 64x32.
// REDUCE=0: write Hout[b][node][512]. REDUCE=1: node-sum -> gp[b][512].
template <int REDUCE>
__global__ __launch_bounds__(1024, 4) void k_fused(const f16* __restrict__ Hin,
                                                   const f16* __restrict__ Wt,
                                                   const float* __restrict__ bias,
                                                   const f16* __restrict__ nA,
                                                   f16* __restrict__ Hout,
                                                   float* __restrict__ gp) {
    __shared__ f16 As[2][16384];   // 2 x (256 rows x 64 f16) = 64 KB
    __shared__ f16 WU[32768];      // stage1: Ws[2][8192]; stage2: U_t 128x256

    const int tid  = threadIdx.x;
    const int lane = tid & 63, wave = tid >> 6;      // wave 0..15
    const int ln15 = lane & 15, quad = lane >> 4;
    const int wm = wave >> 2, wn = wave & 3;

    const int lin = blockIdx.x;
    const int xcd = lin & 7, p = lin >> 3;
    const int grp = xcd * 128 + p;                   // 0..1023
    const int b = grp >> 2, hc = grp & 3;

    const f16* Hb = Hin + (size_t)b * (N_ * H_);
    const f16* Ab = nA + (size_t)b * (N_ * N_);
    const f16* Wc = Wt + (size_t)(hc * 128) * H_;

    const int lr = lane >> 3;
    const int kc = (lane & 7) ^ lr;

    auto stage1 = [&](int buf, int kt) {             // 3 gload_lds per wave
        #pragma unroll
        for (int c = 0; c < 2; c++) {
            int chunk = wave * 2 + c;
            int row = chunk * 8 + lr;
            __builtin_amdgcn_global_load_lds(
                (__attribute__((address_space(1))) void*)(Hb + (size_t)row * H_ + kt * 64 + kc * 8),
                (__attribute__((address_space(3))) void*)(&As[buf][chunk * 512]), 16, 0, 0);
        }
        {
            int chunk = wave;
            int row = chunk * 8 + lr;
            __builtin_amdgcn_global_load_lds(
                (__attribute__((address_space(1))) void*)(Wc + (size_t)row * H_ + kt * 64 + kc * 8),
                (__attribute__((address_space(3))) void*)(&WU[buf * 8192 + chunk * 512]), 16, 0, 0);
        }
    };
    auto stage2 = [&](int buf, int jt) {             // 2 gload_lds per wave
        #pragma unroll
        for (int c = 0; c < 2; c++) {
            int chunk = wave * 2 + c;
            int row = chunk * 8 + lr;
            __builtin_amdgcn_global_load_lds(
                (__attribute__((address_space(1))) void*)(Ab + (size_t)row * N_ + jt * 64 + kc * 8),
                (__attribute__((address_space(3))) void*)(&As[buf][chunk * 512]), 16, 0, 0);
        }
    };

    f32x4 acc[4][2];
    #pragma unroll
    for (int i = 0; i < 4; i++)
        #pragma unroll
        for (int j = 0; j < 2; j++)
            #pragma unroll
            for (int r = 0; r < 4; r++) acc[i][j][r] = 0.0f;

    // ---------------- stage 1: U = Hin @ Wc^T + bias --------------------
    stage1(0, 0);
    for (int kt = 0; kt < 8; ++kt) {
        const int buf = kt & 1;
        if (kt < 7) {
            stage1(buf ^ 1, kt + 1);
            BAR_ACQ(3);
        } else {
            stage2(0, 0);
            BAR_ACQ(2);
        }
        __builtin_amdgcn_s_setprio(1);
        #pragma unroll
        for (int ks = 0; ks < 2; ks++) {
            const int rkc = ks * 4 + quad;
            f16x8 aF[4], bF[2];
            #pragma unroll
            for (int t = 0; t < 4; t++) {
                int ra = wm * 64 + t * 16 + ln15;
                aF[t] = *(const f16x8*)&As[buf][(ra * 8 + (rkc ^ (ra & 7))) * 8];
            }
            #pragma unroll
            for (int t = 0; t < 2; t++) {
                int rb = wn * 32 + t * 16 + ln15;
                bF[t] = *(const f16x8*)&WU[buf * 8192 + (rb * 8 + (rkc ^ (rb & 7))) * 8];
            }
            #pragma unroll
            for (int mt = 0; mt < 4; mt++)
                #pragma unroll
                for (int nt = 0; nt < 2; nt++)
                    acc[mt][nt] = __builtin_amdgcn_mfma_f32_16x16x32_f16(aF[mt], bF[nt], acc[mt][nt], 0, 0, 0);
        }
        __builtin_amdgcn_s_setprio(0);
        BAR_REL();
    }

    // epilogue 1: acc(+bias) -> U_t[h][j] in WU, chunk-swizzled.
    #pragma unroll
    for (int nt = 0; nt < 2; nt++) {
        int hl = wn * 32 + nt * 16 + ln15;
        float bv = bias[hc * 128 + hl];
        #pragma unroll
        for (int mt = 0; mt < 4; mt++) {
            int j = wm * 64 + mt * 16 + quad * 4;
            int slot = (j >> 3) ^ (hl & 7);
            f16x4 v;
            #pragma unroll
            for (int rr = 0; rr < 4; rr++) v[rr] = (f16)(acc[mt][nt][rr] + bv);
            *(f16x4*)&WU[hl * 256 + slot * 8 + (j & 7)] = v;
        }
    }
    asm volatile("s_waitcnt lgkmcnt(0)" ::: "memory");
    __builtin_amdgcn_s_barrier();
    __builtin_amdgcn_sched_barrier(0);

    // ---------------- stage 2: relu(nA @ U) -----------------------------
    #pragma unroll
    for (int i = 0; i < 4; i++)
        #pragma unroll
        for (int j = 0; j < 2; j++)
            #pragma unroll
            for (int r = 0; r < 4; r++) acc[i][j][r] = 0.0f;

    for (int jt = 0; jt < 4; ++jt) {
        const int buf = jt & 1;
        if (jt < 3) {
            stage2(buf ^ 1, jt + 1);
            BAR_ACQ(2);
        } else {
            BAR_ACQ(0);
        }
        __builtin_amdgcn_s_setprio(1);
        #pragma unroll
        for (int ks = 0; ks < 2; ks++) {
            const int rkc = ks * 4 + quad;
            f16x8 aF[4], bF[2];
            #pragma unroll
            for (int t = 0; t < 4; t++) {
                int ra = wm * 64 + t * 16 + ln15;
                aF[t] = *(const f16x8*)&As[buf][(ra * 8 + (rkc ^ (ra & 7))) * 8];
            }
            #pragma unroll
            for (int t = 0; t < 2; t++) {
                int rb = wn * 32 + t * 16 + ln15;
                int g = jt * 8 + rkc;
                bF[t] = *(const f16x8*)&WU[rb * 256 + ((g ^ (rb & 7)) * 8)];
            }
            #pragma unroll
            for (int mt = 0; mt < 4; mt++)
                #pragma unroll
                for (int nt = 0; nt < 2; nt++)
                    acc[mt][nt] = __builtin_amdgcn_mfma_f32_16x16x32_f16(aF[mt], bF[nt], acc[mt][nt], 0, 0, 0);
        }
        __builtin_amdgcn_s_setprio(0);
        BAR_REL();
    }

    if (REDUCE == 0) {
        f16* Ob = Hout + (size_t)b * (N_ * H_);
        #pragma unroll
        for (int mt = 0; mt < 4; mt++) {
            int node = wm * 64 + mt * 16 + quad * 4;
            #pragma unroll
            for (int nt = 0; nt < 2; nt++) {
                int hg = hc * 128 + wn * 32 + nt * 16 + ln15;
                #pragma unroll
                for (int rr = 0; rr < 4; rr++) {
                    float v = acc[mt][nt][rr];
                    v = v > 0.f ? v : 0.f;
                    Ob[(size_t)(node + rr) * H_ + hg] = (f16)v;
                }
            }
        }
    } else {
        float part[2];
        #pragma unroll
        for (int nt = 0; nt < 2; nt++) {
            float s = 0.f;
            #pragma unroll
            for (int mt = 0; mt < 4; mt++)
                #pragma unroll
                for (int rr = 0; rr < 4; rr++) {
                    float v = acc[mt][nt][rr];
                    s += (v > 0.f ? v : 0.f);
                }
            s += __shfl_down(s, 32, 64);
            s += __shfl_down(s, 16, 64);
            part[nt] = s;                            // valid on quad==0 lanes
        }
        __syncthreads();
        float* red = (float*)&As[0][0];              // 16 waves x 32 cols
        if (quad == 0) {
            #pragma unroll
            for (int nt = 0; nt < 2; nt++)
                red[wave * 32 + nt * 16 + ln15] = part[nt];
        }
        __syncthreads();
        if (tid < 128) {
            int wnl = tid >> 5, cl = tid & 31;
            float g = red[(0 * 4 + wnl) * 32 + cl] + red[(1 * 4 + wnl) * 32 + cl]
                    + red[(2 * 4 + wnl) * 32 + cl] + red[(3 * 4 + wnl) * 32 + cl];
            gp[(size_t)b * H_ + hc * 128 + tid] = g;
        }
    }
}

// ---------------------------------------------------------------------------
// k_logits: logits[b] = (gp[b]/N) @ fcw + fcb.  grid B_ x 256.
__global__ __launch_bounds__(256) void k_logits(const float* __restrict__ gp,
                                                const float* __restrict__ fcw,
                                                const float* __restrict__ fcb,
                                                float* __restrict__ out) {
    int b = blockIdx.x, tid = threadIdx.x;
    const float* g = gp + (size_t)b * H_;
    float g0 = g[tid];
    float g1 = g[tid + 256];
    float p0 = g0 * fcw[tid * 2 + 0] + g1 * fcw[(tid + 256) * 2 + 0];
    float p1 = g0 * fcw[tid * 2 + 1] + g1 * fcw[(tid + 256) * 2 + 1];
    for (int off = 32; off; off >>= 1) {
        p0 += __shfl_down(p0, off, 64);
        p1 += __shfl_down(p1, off, 64);
    }
    __shared__ float r0[4], r1[4];
    int lane = tid & 63, w = tid >> 6;
    if (lane == 0) { r0[w] = p0; r1[w] = p1; }
    __syncthreads();
    const float inv = 1.0f / N_;
    if (tid == 0) out[b * 2 + 0] = (r0[0] + r0[1] + r0[2] + r0[3]) * inv + fcb[0];
    if (tid == 1) out[b * 2 + 1] = (r1[0] + r1[1] + r1[2] + r1[3]) * inv + fcb[1];
}

// ---------------------------------------------------------------------------
extern "C" void kernel_launch(void* const* d_in, const int* in_sizes, int n_in,
                              void* d_out, int out_size, void* d_ws, size_t ws_size,
                              hipStream_t stream) {
    const float* z   = (const float*)d_in[0];
    const float* ne  = (const float*)d_in[1];
    const float* w1  = (const float*)d_in[2];
    const float* b1  = (const float*)d_in[3];
    const float* w2  = (const float*)d_in[4];
    const float* b2  = (const float*)d_in[5];
    const float* w3  = (const float*)d_in[6];
    const float* b3  = (const float*)d_in[7];
    const float* fcw = (const float*)d_in[8];
    const float* fcb = (const float*)d_in[9];
    float* out = (float*)d_out;

    char* ws = (char*)d_ws;
    f16*   T     = (f16*)(ws + 0);            // 67,108,864 (T2/T3 intermediate)
    f16*   nA    = (f16*)(ws + 67108864);     // 33,554,432
    f16*   Hh    = (f16*)(ws + 100663296);    // 67,108,864 (H1)
    float* gpart = (float*)(ws + 100663296);  //    524,288 (alias Hh, H1 dead after F2)
    f16*   XW1t  = (f16*)(ws + 167772160);    //    262,144
    f16*   w2t   = (f16*)(ws + 168034304);    //    524,288
    f16*   w3t   = (f16*)(ws + 168558592);    //    524,288

    // Front-end union: fsum(z->nA) + XW1t + w2t/w3t transpose, one launch
    k_front<<<512, 1024, 0, stream>>>(z, ne, w1, b1, w2, w3, nA, XW1t, w2t, w3t);

    // Layer 1: H1 = relu(nA @ XW1)  (16-wave counted-vmcnt transplant)
    k_gemm2<<<512, 1024, 0, stream>>>(nA, XW1t, Hh);
    // Layer 2 fused: H2 = relu(nA @ (H1 @ w2 + b2))
    k_fused<0><<<1024, 1024, 0, stream>>>(Hh, w2t, b2, nA, T, nullptr);
    // Layer 3 fused + readout: gp[b][h] = sum_i relu(nA @ (H2 @ w3 + b3))[i][h]
    k_fused<1><<<1024, 1024, 0, stream>>>(T, w3t, b3, nA, nullptr, gpart);

    k_logits<<<B_, 256, 0, stream>>>(gpart, fcw, fcb, out);
}